// Round 21
// baseline (148.007 us; speedup 1.0000x reference)
//
#include <hip/hip_runtime.h>

// Problem constants: B=8, M=N=256, D=512
#define USTR 192   // pair-planes per batch-dir: u = (row>>1) + lane, 0..190

// Raw HW transcendentals: v_exp_f32 is 2^x, v_log_f32 is log2(x).
#define EXP2F(x) __builtin_amdgcn_exp2f(x)
#define LOG2F(x) __builtin_amdgcn_logf(x)

__device__ __forceinline__ void ld4(float d[4], const float* p) {
  float4 v = *(const float4*)p;
  d[0] = v.x; d[1] = v.y; d[2] = v.z; d[3] = v.w;
}

// ---------------------------------------------------------------------------
// Kernel 1: cost GEMM with FUSED norms, 32x64 tiles (256 blocks).
// Each block streams its 32 x-rows and 64 y-rows in full (K=512), so it
// accumulates the squared norms during staging and reduces them in LDS --
// no separate norms kernel.  Output m = exp2(-cost*ig2), f32 pair-plane
// layout (forward only; the reversed pass reads this lane-reversed):
//   plane u = v + l (v=row-pair, l=col-group lane), lane record = 8 floats
//   {row 2v cols 4l..4l+3, row 2v+1 cols 4l..4l+3}.
// ---------------------------------------------------------------------------
__global__ void __launch_bounds__(256) cost_gemm(const float* __restrict__ x,
                                                 const float* __restrict__ y,
                                                 const float* __restrict__ gamma,
                                                 float* __restrict__ mAll) {
  int b = blockIdx.z, mt = blockIdx.y, nt = blockIdx.x;
  int m0 = mt * 32, n0 = nt * 64;
  __shared__ float Xs[16][36];
  __shared__ float Ys[16][68];
  int tid = threadIdx.x;
  int row = tid >> 2, cq = tid & 3;
  int tx = tid & 15, ty = tid >> 4;
  const float* xb = x + ((size_t)b * 256 + m0) * 512;
  const float* yb = y + ((size_t)b * 256 + n0) * 512;
  float acc[2][4] = {};
  float px = 0.f, py = 0.f;            // squared-norm partials
  for (int k0 = 0; k0 < 512; k0 += 16) {
    float4 xv;
    if (tid < 128) {
      xv = *(const float4*)(xb + (size_t)row * 512 + k0 + cq * 4);
      px += xv.x*xv.x + xv.y*xv.y + xv.z*xv.z + xv.w*xv.w;
    }
    float4 yv = *(const float4*)(yb + (size_t)row * 512 + k0 + cq * 4);
    py += yv.x*yv.x + yv.y*yv.y + yv.z*yv.z + yv.w*yv.w;
    __syncthreads();
    if (tid < 128) {
      Xs[cq*4+0][row] = xv.x; Xs[cq*4+1][row] = xv.y;
      Xs[cq*4+2][row] = xv.z; Xs[cq*4+3][row] = xv.w;
    }
    Ys[cq*4+0][row] = yv.x; Ys[cq*4+1][row] = yv.y;
    Ys[cq*4+2][row] = yv.z; Ys[cq*4+3][row] = yv.w;
    __syncthreads();
#pragma unroll
    for (int kk = 0; kk < 16; ++kk) {
      float a0 = Xs[kk][ty * 2 + 0];
      float a1 = Xs[kk][ty * 2 + 1];
      float4 bv = *(const float4*)(&Ys[kk][tx * 4]);
      float br[4] = {bv.x, bv.y, bv.z, bv.w};
#pragma unroll
      for (int c = 0; c < 4; ++c) {
        acc[0][c] += a0 * br[c];
        acc[1][c] += a1 * br[c];
      }
    }
  }
  // norm reduction: reuse Xs/Ys as flat scratch (sized 576 / 1088 floats)
  __syncthreads();
  float* xsf = &Xs[0][0];
  float* ysf = &Ys[0][0];
  if (tid < 128) xsf[tid] = px;
  ysf[tid] = py;
  __syncthreads();
  float rx[2], ry[4];
#pragma unroll
  for (int r = 0; r < 2; ++r) {
    int lr = ty * 2 + r;
    float s = xsf[lr*4] + xsf[lr*4+1] + xsf[lr*4+2] + xsf[lr*4+3];
    rx[r] = 1.0f / fmaxf(sqrtf(s), 1e-8f);
  }
#pragma unroll
  for (int c = 0; c < 4; ++c) {
    int lc = tx * 4 + c;
    float s = ysf[lc*4] + ysf[lc*4+1] + ysf[lc*4+2] + ysf[lc*4+3];
    ry[c] = 1.0f / fmaxf(sqrtf(s), 1e-8f);
  }
  float gv = fmaxf(fabsf(gamma[0]), 1e-4f);
  float ig2 = 1.4426950408889634f / gv;
  int l = nt * 16 + tx;                  // column-group lane
  int v = mt * 16 + ty;                  // row-pair index
  int u = v + l;                         // pair-plane index
  float* mp = mAll + ((size_t)b * USTR + u) * 512 + l * 8;
#pragma unroll
  for (int r = 0; r < 2; ++r) {
    float c0 = (1.0f - acc[r][0] * rx[r] * ry[0]) * ig2;
    float c1 = (1.0f - acc[r][1] * rx[r] * ry[1]) * ig2;
    float c2 = (1.0f - acc[r][2] * rx[r] * ry[2]) * ig2;
    float c3 = (1.0f - acc[r][3] * rx[r] * ry[3]) * ig2;
    float4 stm = {EXP2F(-c0), EXP2F(-c1), EXP2F(-c2), EXP2F(-c3)};
    *(float4*)(mp + 4 * r) = stm;
  }
}

// ---------------------------------------------------------------------------
// Kernel 2: dual-direction p-pass.  Blocks 0-7: forward p on batch b.
// Blocks 8-15: the same recurrence index-reversed = backward b-pass,
// reading the FORWARD m array lane-reversed (plane 190-t is constant per
// slot -> still one coalesced 2 KB transaction) and writing b DIRECTLY in
// forward layout (so the combine kernel is fully coalesced).
// One wave per block; lane l owns (local) cols 4l..4l+3; slot t processes
// local rows R=2(t-l), R+1 of plane t.  p = P * 2^Q, Q constant per 8-slot
// epoch; E recovered later as p*b/(m*Z).  No transcendentals on the chain.
// ---------------------------------------------------------------------------
__global__ void __launch_bounds__(64, 1) pass_kernel(const float* __restrict__ mAll,
                                                     float* __restrict__ pAll,
                                                     float* __restrict__ QepAll,
                                                     const float* __restrict__ gamma,
                                                     float* __restrict__ dist_out) {
  int blk = blockIdx.x, l = threadIdx.x;
  int dir = blk >> 3, b = blk & 7;
  bool rev = (dir == 1);
  float gv = fmaxf(fabsf(gamma[0]), 1e-4f);
  float gl = gv * 0.6931471805599453f;      // R = q * gl
  const float* mb = mAll + (size_t)b * USTR * 512;
  float* pb = pAll + (size_t)blk * USTR * 512;
  float* qe = QepAll + ((size_t)blk * 64 + l) * 24;
  int lOff = rev ? (63 - l) * 8 : l * 8;
  float Pp0 = 0.f, Pp1 = 0.f, Pp2 = 0.f, Pp3 = 0.f;  // local row R-1 (own)
  float bot0 = 0.f, bot1 = 0.f;   // my col-3 values of last pair (for lane l+1)
  int Q = 0;                       // lane scale: p = P * 2^Q
  float ucar = (l == 0) ? 1.0f : 0.f;  // p(R-1, 4l-1); origin seed p(-1,-1)=1
  float A0[8], A1[8], A2[8], A3[8], A4[8], A5[8], A6[8], A7[8];
  float A8[8], A9[8], A10[8], A11[8], A12[8], A13[8], A14[8], A15[8];
  auto loadC = [&](int t, float* buf) {
    int tc = t > 190 ? 190 : t;
    int u = rev ? (190 - tc) : tc;
    const float* p = mb + (size_t)u * 512 + lOff;
    float tmp[8];
    ld4(tmp, p); ld4(tmp + 4, p + 4);
    if (rev) {
#pragma unroll
      for (int j = 0; j < 8; ++j) buf[j] = tmp[7 - j];
    } else {
#pragma unroll
      for (int j = 0; j < 8; ++j) buf[j] = tmp[j];
    }
  };
  auto body = [&](int t, const float* mm) {
    bool act = (unsigned)(t - l) <= 127u;
    float s0 = __shfl_up(bot0, 1);   // p(R,   4l-1) from lane l-1
    float s1 = __shfl_up(bot1, 1);   // p(R+1, 4l-1)
    int  liQ = __shfl_up(Q, 1);
    if (l == 0) { s0 = 0.f; s1 = 0.f; }
    else { int adj = liQ - Q; s0 = ldexpf(s0, adj); s1 = ldexpf(s1, adj); }
    // local row R
    float v0 = mm[0] * (Pp0 + s0 + ucar);
    float v1 = mm[1] * (Pp1 + v0 + Pp0);
    float v2 = mm[2] * (Pp2 + v1 + Pp1);
    float v3 = mm[3] * (Pp3 + v2 + Pp2);
    // local row R+1
    float w0 = mm[4] * (v0 + s1 + s0);
    float w1 = mm[5] * (v1 + w0 + v0);
    float w2 = mm[6] * (v2 + w1 + v1);
    float w3 = mm[7] * (v3 + w2 + v2);
    if (act) {
      if (!rev) {
        float* sp = pb + (size_t)t * 512 + lOff;
        *(float4*)(sp)     = (float4){v0, v1, v2, v3};
        *(float4*)(sp + 4) = (float4){w0, w1, w2, w3};
        if (l == 63 && t == 190)
          dist_out[b] = (-(float)Q - LOG2F(w3)) * gl;   // distance, off-loop
      } else {
        // write b in FORWARD layout: plane 190-t, lane 63-l, all 8 reversed
        float* sp = pb + (size_t)(190 - t) * 512 + lOff;
        *(float4*)(sp)     = (float4){w3, w2, w1, w0};
        *(float4*)(sp + 4) = (float4){v3, v2, v1, v0};
      }
      Pp0 = w0; Pp1 = w1; Pp2 = w2; Pp3 = w3;
      ucar = s1; bot0 = v3; bot1 = w3;
    }
  };
  auto renorm = [&](int tEnd) {
    if ((unsigned)(tEnd - l) <= 127u) {
      int e = (int)((__float_as_uint(Pp3) >> 23) & 255u) - 127;
      Pp0 = ldexpf(Pp0, -e); Pp1 = ldexpf(Pp1, -e);
      Pp2 = ldexpf(Pp2, -e); Pp3 = ldexpf(Pp3, -e);
      ucar = ldexpf(ucar, -e);
      bot0 = ldexpf(bot0, -e); bot1 = ldexpf(bot1, -e);
      Q += e;
    }
  };
  loadC(0, A0);  loadC(1, A1);  loadC(2, A2);  loadC(3, A3);
  loadC(4, A4);  loadC(5, A5);  loadC(6, A6);  loadC(7, A7);
  loadC(8, A8);  loadC(9, A9);  loadC(10, A10); loadC(11, A11);
  loadC(12, A12); loadC(13, A13); loadC(14, A14); loadC(15, A15);
  for (int it = 0; it < 12; ++it) {   // 12 x 16 = 192 slots; last live 190
    int s = it * 16;
    qe[2 * it] = (float)Q;
    body(s + 0, A0); loadC(s + 16, A0);
    body(s + 1, A1); loadC(s + 17, A1);
    body(s + 2, A2); loadC(s + 18, A2);
    body(s + 3, A3); loadC(s + 19, A3);
    body(s + 4, A4); loadC(s + 20, A4);
    body(s + 5, A5); loadC(s + 21, A5);
    body(s + 6, A6); loadC(s + 22, A6);
    body(s + 7, A7); loadC(s + 23, A7);
    renorm(s + 7);
    qe[2 * it + 1] = (float)Q;
    body(s + 8,  A8);  loadC(s + 24, A8);
    body(s + 9,  A9);  loadC(s + 25, A9);
    body(s + 10, A10); loadC(s + 26, A10);
    body(s + 11, A11); loadC(s + 27, A11);
    body(s + 12, A12); loadC(s + 28, A12);
    body(s + 13, A13); loadC(s + 29, A13);
    body(s + 14, A14); loadC(s + 30, A14);
    body(s + 15, A15); loadC(s + 31, A15);
    renorm(s + 15);
  }
}

// ---------------------------------------------------------------------------
// Kernel 3: posterior combine.  E[r][c] = p * b / (m * Z), Z = p(255,255).
// p = P*2^Qf, b = B*2^Qb, Z = Zp*2^Zq -> E = (P*B)/(M*Zp) * 2^(Qf+Qb-Zq).
// b is stored in forward layout by the reversed pass, so P, B, M are all
// read with IDENTICAL fully-coalesced indices.  Writes row-major float4
// directly to d_out.
// ---------------------------------------------------------------------------
__global__ void __launch_bounds__(256) e_kernel(const float* __restrict__ mAll,
                                                const float* __restrict__ pAll,
                                                const float* __restrict__ QepAll,
                                                float* __restrict__ out) {
  int tid = blockIdx.x * 256 + threadIdx.x;   // = ((b*256 + r)*64 + l)
  int l = tid & 63;
  int r = (tid >> 6) & 255;
  int b = tid >> 14;
  int v = r >> 1, rf = r & 1;
  int uF = v + l;
  size_t off = ((size_t)uF * 512) + l * 8 + rf * 4;
  const float* pF = pAll + (size_t)b * USTR * 512 + off;
  const float* pB = pAll + (size_t)(8 + b) * USTR * 512 + off;
  const float* mF = mAll + (size_t)b * USTR * 512 + off;
  float P[4], Bv[4], M[4];
  ld4(P, pF); ld4(Bv, pB); ld4(M, mF);
  float Qf = QepAll[((size_t)b * 64 + l) * 24 + (uF >> 3)];
  float Qb = QepAll[((size_t)(8 + b) * 64 + (63 - l)) * 24 + ((190 - uF) >> 3)];
  float Zp = pAll[((size_t)b * USTR + 190) * 512 + 63 * 8 + 7];
  float Zq = QepAll[((size_t)b * 64 + 63) * 24 + 23];
  int e = (int)(Qf + Qb - Zq);
  float inv = 1.0f / Zp;
  float4 o;
  o.x = ldexpf(P[0] * Bv[0] / M[0] * inv, e);
  o.y = ldexpf(P[1] * Bv[1] / M[1] * inv, e);
  o.z = ldexpf(P[2] * Bv[2] / M[2] * inv, e);
  o.w = ldexpf(P[3] * Bv[3] / M[3] * inv, e);
  *(float4*)(out + (size_t)b * 65536 + (size_t)r * 256 + 4 * l) = o;
}

// ---------------------------------------------------------------------------
// Workspace (floats), ~9.5 MB:
//   mAll  (8*192*512: potentials, forward pair-planes only)
//   pAll  (16*192*512: p-pass outputs; dirs 8-15 written in forward layout)
//   QepAll (16*64*24: per-block per-lane per-epoch scales)
// Alignment (E) and distance go straight into d_out.
// d_out: alignment [0 .. 524287], distance [524288 .. 524295].
// ---------------------------------------------------------------------------
extern "C" void kernel_launch(void* const* d_in, const int* in_sizes, int n_in,
                              void* d_out, int out_size, void* d_ws, size_t ws_size,
                              hipStream_t stream) {
  const float* x = (const float*)d_in[0];
  const float* y = (const float*)d_in[1];
  const float* gamma = (const float*)d_in[2];
  float* out = (float*)d_out;
  float* ws = (float*)d_ws;

  float* mAll   = ws;
  float* pAll   = mAll + (size_t)8 * USTR * 512;
  float* QepAll = pAll + (size_t)16 * USTR * 512;

  cost_gemm<<<dim3(4, 8, 8), 256, 0, stream>>>(x, y, gamma, mAll);
  pass_kernel<<<16, 64, 0, stream>>>(mAll, pAll, QepAll, gamma, out + 524288);
  e_kernel<<<512, 256, 0, stream>>>(mAll, pAll, QepAll, out);
}

// Round 22
// 127.260 us; speedup vs baseline: 1.1630x; 1.1630x over previous
//
#include <hip/hip_runtime.h>

// Problem constants: B=8, M=N=256, D=512
#define USTR 192   // pair-planes per batch-dir: u = (row>>1) + lane, 0..190

// Raw HW transcendentals: v_exp_f32 is 2^x, v_log_f32 is log2(x).
#define EXP2F(x) __builtin_amdgcn_exp2f(x)
#define LOG2F(x) __builtin_amdgcn_logf(x)

__device__ __forceinline__ void ld4(float d[4], const float* p) {
  float4 v = *(const float4*)p;
  d[0] = v.x; d[1] = v.y; d[2] = v.z; d[3] = v.w;
}

// ---------------------------------------------------------------------------
// Kernel 1: cost GEMM with FUSED norms, 32x64 tiles (256 blocks).
// Each block streams its 32 x-rows and 64 y-rows in full (K=512), so squared
// norms are accumulated during staging and reduced in LDS -- no separate
// norms kernel.  Output m = exp2(-cost*ig2), f32 pair-plane layout, written
// TWICE (as R19 -- each pass direction reads its own copy with an identical
// ascending lane-aligned pattern):
//   forward  (batch-dir b):   plane u = v+l, lane l, rows 2v,2v+1
//   reversed (batch-dir 8+b): plane 190-u, lane 63-l, rows/cols reversed
// ---------------------------------------------------------------------------
__global__ void __launch_bounds__(256) cost_gemm(const float* __restrict__ x,
                                                 const float* __restrict__ y,
                                                 const float* __restrict__ gamma,
                                                 float* __restrict__ mAll) {
  int b = blockIdx.z, mt = blockIdx.y, nt = blockIdx.x;
  int m0 = mt * 32, n0 = nt * 64;
  __shared__ float Xs[16][36];
  __shared__ float Ys[16][68];
  int tid = threadIdx.x;
  int row = tid >> 2, cq = tid & 3;
  int tx = tid & 15, ty = tid >> 4;
  const float* xb = x + ((size_t)b * 256 + m0) * 512;
  const float* yb = y + ((size_t)b * 256 + n0) * 512;
  float acc[2][4] = {};
  float px = 0.f, py = 0.f;            // squared-norm partials
  for (int k0 = 0; k0 < 512; k0 += 16) {
    float4 xv;
    if (tid < 128) {
      xv = *(const float4*)(xb + (size_t)row * 512 + k0 + cq * 4);
      px += xv.x*xv.x + xv.y*xv.y + xv.z*xv.z + xv.w*xv.w;
    }
    float4 yv = *(const float4*)(yb + (size_t)row * 512 + k0 + cq * 4);
    py += yv.x*yv.x + yv.y*yv.y + yv.z*yv.z + yv.w*yv.w;
    __syncthreads();
    if (tid < 128) {
      Xs[cq*4+0][row] = xv.x; Xs[cq*4+1][row] = xv.y;
      Xs[cq*4+2][row] = xv.z; Xs[cq*4+3][row] = xv.w;
    }
    Ys[cq*4+0][row] = yv.x; Ys[cq*4+1][row] = yv.y;
    Ys[cq*4+2][row] = yv.z; Ys[cq*4+3][row] = yv.w;
    __syncthreads();
#pragma unroll
    for (int kk = 0; kk < 16; ++kk) {
      float a0 = Xs[kk][ty * 2 + 0];
      float a1 = Xs[kk][ty * 2 + 1];
      float4 bv = *(const float4*)(&Ys[kk][tx * 4]);
      float br[4] = {bv.x, bv.y, bv.z, bv.w};
#pragma unroll
      for (int c = 0; c < 4; ++c) {
        acc[0][c] += a0 * br[c];
        acc[1][c] += a1 * br[c];
      }
    }
  }
  // norm reduction: reuse Xs/Ys as flat scratch (sized 576 / 1088 floats)
  __syncthreads();
  float* xsf = &Xs[0][0];
  float* ysf = &Ys[0][0];
  if (tid < 128) xsf[tid] = px;
  ysf[tid] = py;
  __syncthreads();
  float rx[2], ry[4];
#pragma unroll
  for (int r = 0; r < 2; ++r) {
    int lr = ty * 2 + r;
    float s = xsf[lr*4] + xsf[lr*4+1] + xsf[lr*4+2] + xsf[lr*4+3];
    rx[r] = 1.0f / fmaxf(sqrtf(s), 1e-8f);
  }
#pragma unroll
  for (int c = 0; c < 4; ++c) {
    int lc = tx * 4 + c;
    float s = ysf[lc*4] + ysf[lc*4+1] + ysf[lc*4+2] + ysf[lc*4+3];
    ry[c] = 1.0f / fmaxf(sqrtf(s), 1e-8f);
  }
  float gv = fmaxf(fabsf(gamma[0]), 1e-4f);
  float ig2 = 1.4426950408889634f / gv;
  int l = nt * 16 + tx;                  // column-group lane
  int v = mt * 16 + ty;                  // row-pair index
  int u = v + l;                         // pair-plane index
  float4 stm[2];
#pragma unroll
  for (int r = 0; r < 2; ++r) {
    float c0 = (1.0f - acc[r][0] * rx[r] * ry[0]) * ig2;
    float c1 = (1.0f - acc[r][1] * rx[r] * ry[1]) * ig2;
    float c2 = (1.0f - acc[r][2] * rx[r] * ry[2]) * ig2;
    float c3 = (1.0f - acc[r][3] * rx[r] * ry[3]) * ig2;
    stm[r] = (float4){EXP2F(-c0), EXP2F(-c1), EXP2F(-c2), EXP2F(-c3)};
  }
  float* mpF = mAll + ((size_t)b * USTR + u) * 512 + l * 8;
  *(float4*)(mpF)     = stm[0];
  *(float4*)(mpF + 4) = stm[1];
  float* mpR = mAll + ((size_t)(8 + b) * USTR + (190 - u)) * 512 + (63 - l) * 8;
  *(float4*)(mpR)     = (float4){stm[1].w, stm[1].z, stm[1].y, stm[1].x};
  *(float4*)(mpR + 4) = (float4){stm[0].w, stm[0].z, stm[0].y, stm[0].x};
}

// ---------------------------------------------------------------------------
// Kernel 2: dual-direction p-pass (R19 verbatim).  Blocks 0-7: forward p on
// batch b.  Blocks 8-15: the SAME recurrence on the reversed m copy =
// backward b-pass.  One wave per block; lane l owns cols 4l..4l+3; slot t
// processes rows R=2(t-l), R+1 of plane u=t.  p = P * 2^Q, Q constant per
// 8-slot epoch (recorded in Qep, renorm at epoch end).  Per slot: 3 shfl +
// 2 ldexp + 24 arith + coalesced 2 KB read + 2 KB write.  E recovered later
// as p*b/(m*Z) -- no weights, no transcendentals on the chain.
// ---------------------------------------------------------------------------
__global__ void __launch_bounds__(64, 1) pass_kernel(const float* __restrict__ mAll,
                                                     float* __restrict__ pAll,
                                                     float* __restrict__ QepAll,
                                                     const float* __restrict__ gamma,
                                                     float* __restrict__ dist_out) {
  int blk = blockIdx.x, l = threadIdx.x;
  int dir = blk >> 3, b = blk & 7;
  float gv = fmaxf(fabsf(gamma[0]), 1e-4f);
  float gl = gv * 0.6931471805599453f;      // R = q * gl
  const float* mb = mAll + (size_t)blk * USTR * 512 + l * 8;
  float* pb = pAll + (size_t)blk * USTR * 512 + l * 8;
  float* qe = QepAll + ((size_t)blk * 64 + l) * 24;
  float Pp0 = 0.f, Pp1 = 0.f, Pp2 = 0.f, Pp3 = 0.f;  // row R-1 (own, scaled)
  float bot0 = 0.f, bot1 = 0.f;   // my col-3 values of last pair (for lane l+1)
  int Q = 0;                       // lane scale: p = P * 2^Q
  float ucar = (l == 0) ? 1.0f : 0.f;  // p(R-1, 4l-1); origin seed p(-1,-1)=1
  float A0[8], A1[8], A2[8], A3[8], A4[8], A5[8], A6[8], A7[8];
  float A8[8], A9[8], A10[8], A11[8], A12[8], A13[8], A14[8], A15[8];
  auto loadC = [&](int t, float* buf) {
    int u = t > 190 ? 190 : t;
    const float* p = mb + (size_t)u * 512;
    ld4(buf, p); ld4(buf + 4, p + 4);
  };
  auto body = [&](int t, const float* mm) {
    bool act = (unsigned)(t - l) <= 127u;
    float s0 = __shfl_up(bot0, 1);   // p(R,   4l-1) from lane l-1
    float s1 = __shfl_up(bot1, 1);   // p(R+1, 4l-1)
    int  liQ = __shfl_up(Q, 1);
    if (l == 0) { s0 = 0.f; s1 = 0.f; }
    else { int adj = liQ - Q; s0 = ldexpf(s0, adj); s1 = ldexpf(s1, adj); }
    // row R
    float v0 = mm[0] * (Pp0 + s0 + ucar);
    float v1 = mm[1] * (Pp1 + v0 + Pp0);
    float v2 = mm[2] * (Pp2 + v1 + Pp1);
    float v3 = mm[3] * (Pp3 + v2 + Pp2);
    // row R+1
    float w0 = mm[4] * (v0 + s1 + s0);
    float w1 = mm[5] * (v1 + w0 + v0);
    float w2 = mm[6] * (v2 + w1 + v1);
    float w3 = mm[7] * (v3 + w2 + v2);
    if (act) {
      float* sp = pb + (size_t)t * 512;
      *(float4*)(sp)     = (float4){v0, v1, v2, v3};
      *(float4*)(sp + 4) = (float4){w0, w1, w2, w3};
      Pp0 = w0; Pp1 = w1; Pp2 = w2; Pp3 = w3;
      ucar = s1; bot0 = v3; bot1 = w3;
      if (dir == 0 && l == 63 && t == 190)
        dist_out[b] = (-(float)Q - LOG2F(w3)) * gl;   // distance, off-loop
    }
  };
  auto renorm = [&](int tEnd) {
    if ((unsigned)(tEnd - l) <= 127u) {
      int e = (int)((__float_as_uint(Pp3) >> 23) & 255u) - 127;
      Pp0 = ldexpf(Pp0, -e); Pp1 = ldexpf(Pp1, -e);
      Pp2 = ldexpf(Pp2, -e); Pp3 = ldexpf(Pp3, -e);
      ucar = ldexpf(ucar, -e);
      bot0 = ldexpf(bot0, -e); bot1 = ldexpf(bot1, -e);
      Q += e;
    }
  };
  loadC(0, A0);  loadC(1, A1);  loadC(2, A2);  loadC(3, A3);
  loadC(4, A4);  loadC(5, A5);  loadC(6, A6);  loadC(7, A7);
  loadC(8, A8);  loadC(9, A9);  loadC(10, A10); loadC(11, A11);
  loadC(12, A12); loadC(13, A13); loadC(14, A14); loadC(15, A15);
  for (int it = 0; it < 12; ++it) {   // 12 x 16 = 192 slots; last live 190
    int s = it * 16;
    qe[2 * it] = (float)Q;
    body(s + 0, A0); loadC(s + 16, A0);
    body(s + 1, A1); loadC(s + 17, A1);
    body(s + 2, A2); loadC(s + 18, A2);
    body(s + 3, A3); loadC(s + 19, A3);
    body(s + 4, A4); loadC(s + 20, A4);
    body(s + 5, A5); loadC(s + 21, A5);
    body(s + 6, A6); loadC(s + 22, A6);
    body(s + 7, A7); loadC(s + 23, A7);
    renorm(s + 7);
    qe[2 * it + 1] = (float)Q;
    body(s + 8,  A8);  loadC(s + 24, A8);
    body(s + 9,  A9);  loadC(s + 25, A9);
    body(s + 10, A10); loadC(s + 26, A10);
    body(s + 11, A11); loadC(s + 27, A11);
    body(s + 12, A12); loadC(s + 28, A12);
    body(s + 13, A13); loadC(s + 29, A13);
    body(s + 14, A14); loadC(s + 30, A14);
    body(s + 15, A15); loadC(s + 31, A15);
    renorm(s + 15);
  }
}

// ---------------------------------------------------------------------------
// Kernel 3: posterior combine (R19 verbatim).  E = p*b/(m*Z), Z = p(255,255).
// p = P*2^Qf, b = B*2^Qb, Z = Zp*2^Zq -> E = (P*B)/(M*Zp) * 2^(Qf+Qb-Zq).
// b(r,c) sits in the REVERSED pass output at plane 190-v-l, lane 63-l,
// half (1-rf), elements reversed.  Writes row-major float4 to d_out.
// ---------------------------------------------------------------------------
__global__ void __launch_bounds__(256) e_kernel(const float* __restrict__ mAll,
                                                const float* __restrict__ pAll,
                                                const float* __restrict__ QepAll,
                                                float* __restrict__ out) {
  int tid = blockIdx.x * 256 + threadIdx.x;   // = ((b*256 + r)*64 + l)
  int l = tid & 63;
  int r = (tid >> 6) & 255;
  int b = tid >> 14;
  int v = r >> 1, rf = r & 1;
  int uF = v + l;
  int uR = 190 - v - l;
  const float* pF  = pAll + ((size_t)b * USTR + uF) * 512 + l * 8 + rf * 4;
  const float* pRv = pAll + ((size_t)(8 + b) * USTR + uR) * 512 + (63 - l) * 8 + (1 - rf) * 4;
  const float* mF  = mAll + ((size_t)b * USTR + uF) * 512 + l * 8 + rf * 4;
  float P[4], Bv[4], M[4];
  ld4(P, pF); ld4(Bv, pRv); ld4(M, mF);
  float Qf = QepAll[((size_t)b * 64 + l) * 24 + (uF >> 3)];
  float Qb = QepAll[((size_t)(8 + b) * 64 + (63 - l)) * 24 + (uR >> 3)];
  float Zp = pAll[((size_t)b * USTR + 190) * 512 + 511];
  float Zq = QepAll[((size_t)b * 64 + 63) * 24 + 23];
  int e = (int)(Qf + Qb - Zq);
  float inv = 1.0f / Zp;
  float4 o;
  o.x = ldexpf(P[0] * Bv[3] / M[0] * inv, e);
  o.y = ldexpf(P[1] * Bv[2] / M[1] * inv, e);
  o.z = ldexpf(P[2] * Bv[1] / M[2] * inv, e);
  o.w = ldexpf(P[3] * Bv[0] / M[3] * inv, e);
  *(float4*)(out + (size_t)b * 65536 + (size_t)r * 256 + 4 * l) = o;
}

// ---------------------------------------------------------------------------
// Workspace (floats), ~12.7 MB:
//   mAll  (16*192*512: potentials, pair-planes; dirs 0-7 fwd, 8-15 reversed)
//   pAll  (16*192*512: p-pass outputs, same layout)
//   QepAll (16*64*24: per-block per-lane per-epoch scales)
// Alignment (E) and distance go straight into d_out.
// d_out: alignment [0 .. 524287], distance [524288 .. 524295].
// ---------------------------------------------------------------------------
extern "C" void kernel_launch(void* const* d_in, const int* in_sizes, int n_in,
                              void* d_out, int out_size, void* d_ws, size_t ws_size,
                              hipStream_t stream) {
  const float* x = (const float*)d_in[0];
  const float* y = (const float*)d_in[1];
  const float* gamma = (const float*)d_in[2];
  float* out = (float*)d_out;
  float* ws = (float*)d_ws;

  const size_t PMAT = (size_t)16 * USTR * 512;
  float* mAll   = ws;
  float* pAll   = mAll + PMAT;
  float* QepAll = pAll + PMAT;

  cost_gemm<<<dim3(4, 8, 8), 256, 0, stream>>>(x, y, gamma, mAll);
  pass_kernel<<<16, 64, 0, stream>>>(mAll, pAll, QepAll, gamma, out + 524288);
  e_kernel<<<512, 256, 0, stream>>>(mAll, pAll, QepAll, out);
}